// Round 7
// baseline (174.820 us; speedup 1.0000x reference)
//
#include <hip/hip_runtime.h>
#include <hip/hip_cooperative_groups.h>
#include <stdint.h>

namespace cg = cooperative_groups;

typedef unsigned short u16;
typedef unsigned int   u32;
typedef int     i32x4  __attribute__((ext_vector_type(4)));
typedef float   f32x4  __attribute__((ext_vector_type(4)));
typedef float   f32x16 __attribute__((ext_vector_type(16)));
typedef __bf16  bf16x8 __attribute__((ext_vector_type(8)));
typedef u32     u32x4  __attribute__((ext_vector_type(4)));
typedef u32     u32x2  __attribute__((ext_vector_type(2)));

union BF8 { bf16x8 v; u16 s[8]; u32x4 q; };

__device__ __forceinline__ u16 f2b_rne(float f) {
    u32 u = __builtin_bit_cast(u32, f);
    u32 r = u + 0x7FFFu + ((u >> 16) & 1u);
    return (u16)(r >> 16);
}
__device__ __forceinline__ u16 f2b_trunc(float f) {
    return (u16)(__builtin_bit_cast(u32, f) >> 16);
}
__device__ __forceinline__ float b2f(u16 h) {
    u32 u = ((u32)h) << 16;
    return __builtin_bit_cast(float, u);
}
__device__ __forceinline__ bf16x8 ld_bf8(const u16* p) {
    BF8 t; t.q = *(const u32x4*)p; return t.v;
}
__device__ __forceinline__ f32x16 zero16() {
    f32x16 z;
#pragma unroll
    for (int i = 0; i < 16; i++) z[i] = 0.f;
    return z;
}
__device__ __forceinline__ f32x4 zero4() {
    f32x4 z;
#pragma unroll
    for (int i = 0; i < 4; i++) z[i] = 0.f;
    return z;
}

#define SCALE2 0.1275312959479341f        /* log2(e)/sqrt(128) */

// AO LDS tile [32 rows][128 cols] u16, XOR-swizzled in 16B column-blocks.
__device__ __forceinline__ void st_ao(u16* aob, int row, int col, u16 v) {
    int blk = (col >> 3) ^ (row & 15);
    aob[row * 128 + blk * 8 + (col & 7)] = v;
}

// ---------------------------------------------------------------------------
// ONE cooperative kernel (grid 256 x 448, 1 block/CU, trivially co-resident):
//  PHASE A = projection: 3072 wave-items (typ in {Q,K,V} x 256 row-blocks x
//    4 col-waves) strided over 1792 global waves. Mask scan is wave-local
//    (shuffle scan); compact positions pass through a per-wave 128 B LDS
//    buffer (same-wave LDS write->read, in-order — the pattern the verified
//    P-tile loop already uses). K pads NOT zeroed (phase-B tail guards
//    sanitize poison); VT pads zeroed (P=0 x NaN = NaN); Larr[b] written by
//    the (typ=V, xb=b*64, ct=0) item.
//  grid.sync() — official cooperative barrier at a QUIESCENT point (R4
//    lesson: fences must not fire while other blocks stream; here all blocks
//    fence together between phases; runtime owns + initializes barrier state).
//  PHASE B = attn + fin, byte-identical to the verified R6 kernel.
// ---------------------------------------------------------------------------
__global__ __launch_bounds__(448, 2) void fused_kernel(
    const float* __restrict__ x, const float* __restrict__ wq,
    const float* __restrict__ wk, const float* __restrict__ wv,
    const int* __restrict__ mask,
    const float* __restrict__ lw, const float* __restrict__ lb,
    u16* Qph, u16* Qpl, u16* Kph, u16* Kpl, u16* VT,
    int* Larr, float* __restrict__ out)
{
    __shared__ char smem[22528];
    int wave = threadIdx.x >> 6;
    int lane = threadIdx.x & 63;
    int m = lane & 31, kg = lane >> 5;

    // ==================== PHASE A: projection ====================
    {
        int* wbuf = (int*)smem + wave * 32;    // per-wave compact-pos buffer
        int gw = blockIdx.x * 7 + wave;        // 0..1791

        for (int item = gw; item < 3072; item += 1792) {
            int typ = item >> 10;              // 0=Q 1=K 2=V
            int sub = item & 1023;
            int xb = sub >> 2, ct = sub & 3;
            int r0 = xb * 32;
            int b = r0 >> 11, sl = r0 & 2047;
            int c = ct * 32 + m;
            int Lw = 0;

            if (typ != 0) {                    // wave-local mask scan
                const int* mp = mask + b * 2048 + lane * 32;
                int mv[32]; int cntv = 0;
#pragma unroll
                for (int j4 = 0; j4 < 8; j4++) {
                    i32x4 t = *(const i32x4*)(mp + j4 * 4);
#pragma unroll
                    for (int q = 0; q < 4; q++) {
                        mv[j4 * 4 + q] = t[q];
                        cntv += (t[q] != 0);
                    }
                }
                int off = cntv;                // inclusive scan over 64 lanes
#pragma unroll
                for (int d = 1; d < 64; d <<= 1) {
                    int o = __shfl_up(off, d, 64);
                    if (lane >= d) off += o;
                }
                Lw = __shfl(off, 63, 64);
                int src = xb & 63;             // lane owning rows sl..sl+31
                if (lane == src) {
                    int p = off - cntv;        // exclusive prefix
#pragma unroll
                    for (int j = 0; j < 32; j++) {
                        wbuf[j] = mv[j] ? p : -1;
                        p += (mv[j] != 0);
                    }
                }
            }

            const float* wp = (typ == 0) ? wq : (typ == 1) ? wk : wv;
            f32x16 acc = zero16();
#pragma unroll 4
            for (int kk = 0; kk < 128; kk += 16) {
                const float* xp = x + (size_t)(r0 + m) * 128 + kk + kg * 8;
                f32x4 x0 = *(const f32x4*)xp;
                f32x4 x1 = *(const f32x4*)(xp + 4);
                BF8 ah, al;
#pragma unroll
                for (int j = 0; j < 4; j++) {
                    u16 hb = f2b_trunc(x0[j]);
                    ah.s[j] = hb; al.s[j] = f2b_trunc(x0[j] - b2f(hb));
                    u16 hb2 = f2b_trunc(x1[j]);
                    ah.s[4 + j] = hb2; al.s[4 + j] = f2b_trunc(x1[j] - b2f(hb2));
                }
                const float* wcol = wp + (size_t)(kk + kg * 8) * 128 + c;
                if (typ < 2) {
                    BF8 bh, bl_;
#pragma unroll
                    for (int j = 0; j < 8; j++) {
                        float w = wcol[(size_t)j * 128];
                        u16 hb = f2b_trunc(w);
                        bh.s[j] = hb; bl_.s[j] = f2b_trunc(w - b2f(hb));
                    }
                    acc = __builtin_amdgcn_mfma_f32_32x32x16_bf16(ah.v, bh.v, acc, 0, 0, 0);
                    acc = __builtin_amdgcn_mfma_f32_32x32x16_bf16(ah.v, bl_.v, acc, 0, 0, 0);
                    acc = __builtin_amdgcn_mfma_f32_32x32x16_bf16(al.v, bh.v, acc, 0, 0, 0);
                } else {
                    BF8 bh;
#pragma unroll
                    for (int j = 0; j < 8; j++) bh.s[j] = f2b_rne(wcol[(size_t)j * 128]);
                    acc = __builtin_amdgcn_mfma_f32_32x32x16_bf16(ah.v, bh.v, acc, 0, 0, 0);
                }
            }

            int hh = c >> 4, d = c & 15;
            if (typ == 0) {
                if (hh != 7) {                 // head 7 never consumed
                    size_t hb_off = (size_t)(b * 8 + hh) * 2048 * 16 + d;
#pragma unroll
                    for (int r = 0; r < 16; r++) {
                        int row = (r & 3) + 8 * (r >> 2) + 4 * kg;
                        float v = acc[r] * SCALE2;
                        u16 hi = f2b_trunc(v);
                        size_t idx = hb_off + (size_t)(sl + row) * 16;
                        Qph[idx] = hi;
                        Qpl[idx] = f2b_trunc(v - b2f(hi));
                    }
                }
            } else if (typ == 1) {
                if (hh != 7) {
                    size_t hb_off = (size_t)(b * 8 + hh) * 2048 * 16 + d;
#pragma unroll
                    for (int r = 0; r < 16; r++) {
                        int row = (r & 3) + 8 * (r >> 2) + 4 * kg;
                        int p = wbuf[row];
                        if (p < 0) continue;   // masked key: dropped
                        float v = acc[r];
                        u16 hi = f2b_trunc(v);
                        size_t idx = hb_off + (size_t)p * 16;
                        Kph[idx] = hi;
                        Kpl[idx] = f2b_trunc(v - b2f(hi));
                    }
                }
            } else {
                if (hh != 7) {
#pragma unroll
                    for (int rg = 0; rg < 4; rg++) {
#pragma unroll
                        for (int q = 0; q < 4; q++) {
                            int row = rg * 8 + 4 * kg + q;
                            int p = wbuf[row];
                            if (p >= 0)
                                VT[(size_t)(b * 128 + c) * 2048 + p] =
                                    f2b_rne(acc[rg * 4 + q]);
                        }
                    }
                }
                // VT pad zeroing (this wave covers its ct-quarter of slice)
                int npad = (Lw + 127) & ~127; if (npad < 128) npad = 128;
                int padn = npad - Lw;
                int slice = xb & 63;
                if (padn > 0) {
                    int e = slice * 256 + ct * 64 + lane;  // 16384 = 128x128
                    int k = e & 127, cc = e >> 7;
                    if (k < padn) VT[(size_t)(b * 128 + cc) * 2048 + (Lw + k)] = 0;
                }
                if (slice == 0 && ct == 0 && lane == 0) Larr[b] = Lw;
            }
        }
    }

    cg::this_grid().sync();                    // quiescent phase boundary

    // ==================== PHASE B: attn + fin (R6 verbatim) ====================
    u16* pbuf = (u16*)smem;                  // 7 x [32][32] u16 = 14336 B
    u16* aob  = (u16*)(smem + 14336);        // [32][128] u16 = 8192 B

    int bid = blockIdx.x;                    // 0..255
    int b = bid >> 6, qt = bid & 63;
    int qs = qt * 32;
    int h = wave;

    int L = Larr[b];
    int npad = (L + 127) & ~127; if (npad < 128) npad = 128;

    size_t headoff = (size_t)(b * 8 + h) * 2048 * 16;
    bf16x8 qfh = ld_bf8(Qph + headoff + (size_t)(qs + m) * 16 + kg * 8);
    bf16x8 qfl = ld_bf8(Qpl + headoff + (size_t)(qs + m) * 16 + kg * 8);
    const u16* kbh = Kph + headoff;
    const u16* kbl = Kpl + headoff;

    // ---- pass 1: per-query max of approx scores (K hi x Q hi), pads excluded ----
    float mloc = -3.0e38f;
    {
        bf16x8 khc = ld_bf8(kbh + (size_t)m * 16 + kg * 8);
        for (int t = 0; t < npad; t += 32) {
            int tn = (t + 32 < npad) ? (t + 32) : 0;
            bf16x8 khn = ld_bf8(kbh + (size_t)(tn + m) * 16 + kg * 8);
            f32x16 sc = __builtin_amdgcn_mfma_f32_32x32x16_bf16(khc, qfh, zero16(), 0, 0, 0);
            if (t + 32 <= L) {
#pragma unroll
                for (int r = 0; r < 16; r++) mloc = fmaxf(mloc, sc[r]);
            } else {
#pragma unroll
                for (int r = 0; r < 16; r++) {
                    int key = t + (r & 3) + 8 * (r >> 2) + 4 * kg;
                    if (key < L) mloc = fmaxf(mloc, sc[r]);
                }
            }
            khc = khn;
        }
    }
    float mrow = fmaxf(mloc, __shfl_xor(mloc, 32, 64));  // per-lane (query m)

    // ---- pass 2: exact scores -> exp2 -> swizzled P tile -> PV + ones ----
    f32x4 o0 = zero4(), o1 = zero4(), l0 = zero4(), l1 = zero4();
    BF8 onesu;
#pragma unroll
    for (int j = 0; j < 8; j++) onesu.s[j] = 0x3F80;
    bf16x8 ones = onesu.v;

    int q16 = lane & 15, krow = lane >> 4;
    const u16* vtb = VT + (size_t)(b * 128 + h * 16 + q16) * 2048;
    int msw = (m >> 1) & 3;                                  // write swizzle
    int qsw = (q16 >> 1) & 3;                                // read swizzle
    u16* pwb = pbuf + wave * 1024 + m * 32 + kg * 4;
    const u16* pr0 = pbuf + wave * 1024 + q16 * 32 + ((krow ^ qsw) * 8);
    const u16* pr1 = pr0 + 16 * 32;

    bf16x8 khc = ld_bf8(kbh + (size_t)m * 16 + kg * 8);
    bf16x8 klc = ld_bf8(kbl + (size_t)m * 16 + kg * 8);

    for (int t = 0; t < npad; t += 32) {
        int tn = (t + 32 < npad) ? (t + 32) : 0;
        bf16x8 khn = ld_bf8(kbh + (size_t)(tn + m) * 16 + kg * 8);
        bf16x8 kln = ld_bf8(kbl + (size_t)(tn + m) * 16 + kg * 8);
        bf16x8 vf  = ld_bf8(vtb + t + krow * 8);

        f32x16 sc = zero16();
        sc = __builtin_amdgcn_mfma_f32_32x32x16_bf16(khc, qfl, sc, 0, 0, 0);
        sc = __builtin_amdgcn_mfma_f32_32x32x16_bf16(klc, qfh, sc, 0, 0, 0);
        sc = __builtin_amdgcn_mfma_f32_32x32x16_bf16(khc, qfh, sc, 0, 0, 0);
        bool tail = (t + 32 > L);                    // wave-uniform
#pragma unroll
        for (int rg = 0; rg < 4; rg++) {
            float e0 = __builtin_amdgcn_exp2f(sc[rg * 4 + 0] - mrow);
            float e1 = __builtin_amdgcn_exp2f(sc[rg * 4 + 1] - mrow);
            float e2 = __builtin_amdgcn_exp2f(sc[rg * 4 + 2] - mrow);
            float e3 = __builtin_amdgcn_exp2f(sc[rg * 4 + 3] - mrow);
            if (tail) {                              // zero pad-key weights
                int kb = t + rg * 8 + kg * 4;
                e0 = (kb + 0 < L) ? e0 : 0.f;
                e1 = (kb + 1 < L) ? e1 : 0.f;
                e2 = (kb + 2 < L) ? e2 : 0.f;
                e3 = (kb + 3 < L) ? e3 : 0.f;
            }
            u32x2 pk;
            pk[0] = __builtin_amdgcn_perm(__builtin_bit_cast(u32, e1),
                                          __builtin_bit_cast(u32, e0), 0x07060302u);
            pk[1] = __builtin_amdgcn_perm(__builtin_bit_cast(u32, e3),
                                          __builtin_bit_cast(u32, e2), 0x07060302u);
            *(u32x2*)(pwb + ((rg ^ msw) * 8)) = pk;   // keys rg*8+4kg..+3, query m
        }
        bf16x8 p0 = *(const bf16x8*)pr0;
        bf16x8 p1 = *(const bf16x8*)pr1;
        o0 = __builtin_amdgcn_mfma_f32_16x16x32_bf16(p0, vf, o0, 0, 0, 0);
        o1 = __builtin_amdgcn_mfma_f32_16x16x32_bf16(p1, vf, o1, 0, 0, 0);
        l0 = __builtin_amdgcn_mfma_f32_16x16x32_bf16(p0, ones, l0, 0, 0, 0);
        l1 = __builtin_amdgcn_mfma_f32_16x16x32_bf16(p1, ones, l1, 0, 0, 0);
        khc = khn; klc = kln;
    }

    // ---- epilogue: normalize in-wave, write AO slice to swizzled LDS tile ----
    int slot0 = (h == 0) ? 0 : h + 1;
#pragma unroll
    for (int j = 0; j < 4; j++) {
        int row0 = krow * 4 + j;
        u16 v0 = f2b_rne(o0[j] * __builtin_amdgcn_rcpf(l0[j]));
        u16 v1 = f2b_rne(o1[j] * __builtin_amdgcn_rcpf(l1[j]));
        int col = slot0 * 16 + q16;
        st_ao(aob, row0,      col, v0);
        st_ao(aob, row0 + 16, col, v1);
        if (h == 1) {                         // buggy-concat duplicate slot
            st_ao(aob, row0,      16 + q16, v0);
            st_ao(aob, row0 + 16, 16 + q16, v1);
        }
    }

    __syncthreads();                          // AO tile complete
    if (threadIdx.x >= 256) return;           // waves 4-6 done

    // ---- fin (waves 0-3): out[qs..qs+31][0..127] = AO @ lw^T + lb ----
    int ct2 = threadIdx.x >> 6;
    int c = ct2 * 32 + m;
    int r0 = b * 2048 + qs;
    f32x16 acc = zero16();
#pragma unroll 4
    for (int kk = 0; kk < 128; kk += 16) {
        int col0 = kk + kg * 8;
        int blk = (col0 >> 3) ^ (m & 15);
        bf16x8 af = *(const bf16x8*)(aob + m * 128 + blk * 8);
        const float* wp2 = lw + (size_t)c * 128 + col0;
        f32x4 w0 = *(const f32x4*)wp2;
        f32x4 w1 = *(const f32x4*)(wp2 + 4);
        BF8 bfr;
#pragma unroll
        for (int j = 0; j < 4; j++) {
            bfr.s[j]     = f2b_rne(w0[j]);
            bfr.s[4 + j] = f2b_rne(w1[j]);
        }
        acc = __builtin_amdgcn_mfma_f32_32x32x16_bf16(af, bfr.v, acc, 0, 0, 0);
    }
    float bias = lb[c];
#pragma unroll
    for (int r = 0; r < 16; r++) {
        int row = (r & 3) + 8 * (r >> 2) + 4 * kg;
        out[(size_t)(r0 + row) * 128 + c] = acc[r] + bias;
    }
}

// ---------------------------------------------------------------------------
extern "C" void kernel_launch(void* const* d_in, const int* in_sizes, int n_in,
                              void* d_out, int out_size, void* d_ws, size_t ws_size,
                              hipStream_t stream)
{
    const float* x    = (const float*)d_in[0];
    const int*   mask = (const int*)d_in[1];
    const float* wq   = (const float*)d_in[2];
    const float* wk   = (const float*)d_in[3];
    const float* wv   = (const float*)d_in[4];
    const float* lw   = (const float*)d_in[5];
    const float* lb   = (const float*)d_in[6];
    float* out = (float*)d_out;

    char* ws = (char*)d_ws;
    u16* Qph = (u16*)(ws + 0 * 2097152);
    u16* Qpl = (u16*)(ws + 1 * 2097152);
    u16* Kph = (u16*)(ws + 2 * 2097152);
    u16* Kpl = (u16*)(ws + 3 * 2097152);
    u16* VT  = (u16*)(ws + 4 * 2097152);
    int* Larr = (int*)(ws + 5 * 2097152);            // 4 int

    void* args[] = {
        (void*)&x, (void*)&wq, (void*)&wk, (void*)&wv, (void*)&mask,
        (void*)&lw, (void*)&lb,
        (void*)&Qph, (void*)&Qpl, (void*)&Kph, (void*)&Kpl, (void*)&VT,
        (void*)&Larr, (void*)&out
    };
    hipLaunchCooperativeKernel((void*)fused_kernel, dim3(256), dim3(448),
                               args, 0, stream);
}

// Round 8
// 107.142 us; speedup vs baseline: 1.6317x; 1.6317x over previous
//
#include <hip/hip_runtime.h>
#include <stdint.h>

typedef unsigned short u16;
typedef unsigned int   u32;
typedef int     i32x4  __attribute__((ext_vector_type(4)));
typedef float   f32x4  __attribute__((ext_vector_type(4)));
typedef float   f32x16 __attribute__((ext_vector_type(16)));
typedef __bf16  bf16x8 __attribute__((ext_vector_type(8)));
typedef u32     u32x4  __attribute__((ext_vector_type(4)));
typedef u32     u32x2  __attribute__((ext_vector_type(2)));

union BF8 { bf16x8 v; u16 s[8]; u32x4 q; };

__device__ __forceinline__ u16 f2b_rne(float f) {
    u32 u = __builtin_bit_cast(u32, f);
    u32 r = u + 0x7FFFu + ((u >> 16) & 1u);
    return (u16)(r >> 16);
}
__device__ __forceinline__ u16 f2b_trunc(float f) {
    return (u16)(__builtin_bit_cast(u32, f) >> 16);
}
__device__ __forceinline__ float b2f(u16 h) {
    u32 u = ((u32)h) << 16;
    return __builtin_bit_cast(float, u);
}
__device__ __forceinline__ bf16x8 ld_bf8(const u16* p) {
    BF8 t; t.q = *(const u32x4*)p; return t.v;
}
__device__ __forceinline__ f32x16 zero16() {
    f32x16 z;
#pragma unroll
    for (int i = 0; i < 16; i++) z[i] = 0.f;
    return z;
}
__device__ __forceinline__ f32x4 zero4() {
    f32x4 z;
#pragma unroll
    for (int i = 0; i < 4; i++) z[i] = 0.f;
    return z;
}

#define SCALE2 0.1275312959479341f        /* log2(e)/sqrt(128) */

// AO LDS tile [32 rows][128 cols] u16, XOR-swizzled in 16B column-blocks.
__device__ __forceinline__ void st_ao(u16* aob, int row, int col, u16 v) {
    int blk = (col >> 3) ^ (row & 15);
    aob[row * 128 + blk * 8 + (col & 7)] = v;
}

// ---------------------------------------------------------------------------
// projection (verified R3/R6 version):
//  - K/V blocks: 64-lane shuffle scan of the batch mask (wave 0) -> compact
//    positions for this block's 32 rows in LDS; masked keys dropped at store.
//  - Q by query index; K hi/lo + V^T by compact key position.
//  - K pads NOT zeroed (attn tail guards sanitize poison); VT pads MUST be
//    zero (P=0 x NaN = NaN): 64 V-blocks per batch zero them cooperatively;
//    slice-0 V-block writes Larr[b].
//  grid (256,3) x 256.
// ---------------------------------------------------------------------------
__global__ __launch_bounds__(256) void proj_kernel(
    const float* __restrict__ x, const float* __restrict__ wq,
    const float* __restrict__ wk, const float* __restrict__ wv,
    const int* __restrict__ mask, int* __restrict__ Larr,
    u16* Qph, u16* Qpl, u16* Kph, u16* Kpl, u16* VT)
{
    int typ  = blockIdx.y;                 // 0=Q 1=K 2=V
    int ct   = threadIdx.x >> 6;
    int lane = threadIdx.x & 63;
    int m = lane & 31, kg = lane >> 5;
    int r0 = blockIdx.x * 32;
    int c = ct * 32 + m;
    int b = r0 >> 11, sl = r0 & 2047;

    __shared__ int pos_sh[32];             // compact pos for rows sl..sl+31 (-1 = masked)
    __shared__ int Lsh;                    // unmasked-key count for batch b

    if (typ != 0) {
        if (threadIdx.x < 64) {            // wave 0: full-batch scan
            int tl = threadIdx.x;
            const int* mp = mask + b * 2048 + tl * 32;
            int mv[32]; int cntv = 0;
#pragma unroll
            for (int j4 = 0; j4 < 8; j4++) {
                i32x4 t = *(const i32x4*)(mp + j4 * 4);
#pragma unroll
                for (int q = 0; q < 4; q++) {
                    mv[j4 * 4 + q] = t[q];
                    cntv += (t[q] != 0);
                }
            }
            int off = cntv;                // inclusive scan over 64 lanes
#pragma unroll
            for (int d = 1; d < 64; d <<= 1) {
                int o = __shfl_up(off, d, 64);
                if (tl >= d) off += o;
            }
            if (tl == 63) Lsh = off;
            if (tl == (sl >> 5)) {         // this lane owns rows sl..sl+31
                int p = off - cntv;        // exclusive prefix
#pragma unroll
                for (int j = 0; j < 32; j++) {
                    pos_sh[j] = mv[j] ? p : -1;
                    p += (mv[j] != 0);
                }
            }
        }
        __syncthreads();
    }

    const float* wp = (typ == 0) ? wq : (typ == 1) ? wk : wv;

    f32x16 acc = zero16();
#pragma unroll 4
    for (int kk = 0; kk < 128; kk += 16) {
        const float* xp = x + (size_t)(r0 + m) * 128 + kk + kg * 8;
        f32x4 x0 = *(const f32x4*)xp;
        f32x4 x1 = *(const f32x4*)(xp + 4);
        BF8 ah, al;
#pragma unroll
        for (int j = 0; j < 4; j++) {
            u16 hb = f2b_trunc(x0[j]);
            ah.s[j] = hb; al.s[j] = f2b_trunc(x0[j] - b2f(hb));
            u16 hb2 = f2b_trunc(x1[j]);
            ah.s[4 + j] = hb2; al.s[4 + j] = f2b_trunc(x1[j] - b2f(hb2));
        }
        const float* wcol = wp + (size_t)(kk + kg * 8) * 128 + c;
        if (typ < 2) {
            BF8 bh, bl_;
#pragma unroll
            for (int j = 0; j < 8; j++) {
                float w = wcol[(size_t)j * 128];
                u16 hb = f2b_trunc(w);
                bh.s[j] = hb; bl_.s[j] = f2b_trunc(w - b2f(hb));
            }
            acc = __builtin_amdgcn_mfma_f32_32x32x16_bf16(ah.v, bh.v, acc, 0, 0, 0);
            acc = __builtin_amdgcn_mfma_f32_32x32x16_bf16(ah.v, bl_.v, acc, 0, 0, 0);
            acc = __builtin_amdgcn_mfma_f32_32x32x16_bf16(al.v, bh.v, acc, 0, 0, 0);
        } else {
            BF8 bh;
#pragma unroll
            for (int j = 0; j < 8; j++) bh.s[j] = f2b_rne(wcol[(size_t)j * 128]);
            acc = __builtin_amdgcn_mfma_f32_32x32x16_bf16(ah.v, bh.v, acc, 0, 0, 0);
        }
    }

    int hh = c >> 4, d = c & 15;
    if (typ == 0) {
        if (hh == 7) return;                      // head 7 never consumed
        size_t hb_off = (size_t)(b * 8 + hh) * 2048 * 16 + d;
#pragma unroll
        for (int r = 0; r < 16; r++) {
            int row = (r & 3) + 8 * (r >> 2) + 4 * kg;
            float v = acc[r] * SCALE2;
            u16 hi = f2b_trunc(v);
            size_t idx = hb_off + (size_t)(sl + row) * 16;
            Qph[idx] = hi;
            Qpl[idx] = f2b_trunc(v - b2f(hi));
        }
    } else if (typ == 1) {
        if (hh == 7) return;
        size_t hb_off = (size_t)(b * 8 + hh) * 2048 * 16 + d;
#pragma unroll
        for (int r = 0; r < 16; r++) {
            int row = (r & 3) + 8 * (r >> 2) + 4 * kg;
            int p = pos_sh[row];
            if (p < 0) continue;                  // masked key: dropped
            float v = acc[r];
            u16 hi = f2b_trunc(v);
            size_t idx = hb_off + (size_t)p * 16;
            Kph[idx] = hi;
            Kpl[idx] = f2b_trunc(v - b2f(hi));
        }
    } else {
        if (hh != 7) {
#pragma unroll
            for (int rg = 0; rg < 4; rg++) {
#pragma unroll
                for (int q = 0; q < 4; q++) {
                    int row = rg * 8 + 4 * kg + q;  // acc r = rg*4+q -> key sl+row
                    int p = pos_sh[row];
                    if (p >= 0)
                        VT[(size_t)(b * 128 + c) * 2048 + p] = f2b_rne(acc[rg * 4 + q]);
                }
            }
        }
        // ---- VT pad zeroing + Larr (V blocks only; 64 slices per batch) ----
        int L = Lsh;
        int npad = (L + 127) & ~127; if (npad < 128) npad = 128;
        int padn = npad - L;
        int slice = blockIdx.x & 63;
        if (padn > 0) {
            int e = slice * 256 + threadIdx.x;    // 64x256 = 16384 = 128x128
            int k = e & 127, cc = e >> 7;
            if (k < padn) VT[(size_t)(b * 128 + cc) * 2048 + (L + k)] = 0;
        }
        if (slice == 0 && threadIdx.x == 0) Larr[b] = L;
    }
}

// ---------------------------------------------------------------------------
// fused attention + final linear (R6 structure) with SINGLE-PASS online
// softmax (defer-8, T13):
//  - pass 1 deleted: per tile, exact 3-MFMA scores -> tile max (pad-guarded
//    + one shfl_xor) -> rescale o/l only when __any(tmax > m_run + 8)
//    (wave-vote, wave-uniform branch). Scale broadcast QK-layout -> PV-layout
//    through a 128 B per-wave LDS scratch (wave-synchronous, in-order — same
//    pattern as the P tile). P bounded by 2^8: bf16 relative precision
//    unchanged; f32 l/o accumulators have ample headroom.
//  - first tile: m_run=-3e38 -> scale=exp2(-inf)=0 on o=l=0 (benign);
//    all-pad tail tiles leave tmax=-3e38 and skip the trigger.
//  - K hi/lo and V each read ONCE per key now (pass-1 K re-read gone).
//  - no cross-block communication; no fences (R4); no grid.sync (R7:
//    cooperative sync measured ~75 us on gfx950 — never use in hot path).
// ---------------------------------------------------------------------------
__global__ __launch_bounds__(448, 2) void attn_kernel(
    const u16* __restrict__ Qph, const u16* __restrict__ Qpl,
    const u16* __restrict__ Kph, const u16* __restrict__ Kpl,
    const u16* __restrict__ VT, const int* __restrict__ Larr,
    const float* __restrict__ lw, const float* __restrict__ lb,
    float* __restrict__ out)
{
    __shared__ char smem[23552];
    u16*   pbuf = (u16*)smem;                // 7 x [32][32] u16 = 14336 B (per-wave, swizzled)
    u16*   aob  = (u16*)(smem + 14336);      // [32][128] u16 = 8192 B (st_ao swizzle)
    float* sclb = (float*)(smem + 22528);    // 7 x [32] f32 = 896 B (per-wave scale bcast)

    int bid = blockIdx.x;                    // 0..255
    int b = bid >> 6, qt = bid & 63;
    int wave = threadIdx.x >> 6;             // = head h (0..6)
    int lane = threadIdx.x & 63;
    int m = lane & 31, kg = lane >> 5;
    int qs = qt * 32;
    int h = wave;

    int L = Larr[b];
    int npad = (L + 127) & ~127; if (npad < 128) npad = 128;

    size_t headoff = (size_t)(b * 8 + h) * 2048 * 16;
    bf16x8 qfh = ld_bf8(Qph + headoff + (size_t)(qs + m) * 16 + kg * 8);
    bf16x8 qfl = ld_bf8(Qpl + headoff + (size_t)(qs + m) * 16 + kg * 8);
    const u16* kbh = Kph + headoff;
    const u16* kbl = Kpl + headoff;

    // ---- single pass: scores -> online max (defer-8) -> exp2 -> P -> PV ----
    f32x4 o0 = zero4(), o1 = zero4(), l0 = zero4(), l1 = zero4();
    float m_run = -3.0e38f;
    BF8 onesu;
#pragma unroll
    for (int j = 0; j < 8; j++) onesu.s[j] = 0x3F80;
    bf16x8 ones = onesu.v;

    int q16 = lane & 15, krow = lane >> 4;
    const u16* vtb = VT + (size_t)(b * 128 + h * 16 + q16) * 2048;
    int msw = (m >> 1) & 3;                                  // write swizzle
    int qsw = (q16 >> 1) & 3;                                // read swizzle
    u16* pwb = pbuf + wave * 1024 + m * 32 + kg * 4;
    const u16* pr0 = pbuf + wave * 1024 + q16 * 32 + ((krow ^ qsw) * 8);
    const u16* pr1 = pr0 + 16 * 32;
    float* scl = sclb + wave * 32;

    bf16x8 khc = ld_bf8(kbh + (size_t)m * 16 + kg * 8);
    bf16x8 klc = ld_bf8(kbl + (size_t)m * 16 + kg * 8);

    for (int t = 0; t < npad; t += 32) {
        int tn = (t + 32 < npad) ? (t + 32) : 0;
        bf16x8 khn = ld_bf8(kbh + (size_t)(tn + m) * 16 + kg * 8);
        bf16x8 kln = ld_bf8(kbl + (size_t)(tn + m) * 16 + kg * 8);
        bf16x8 vf  = ld_bf8(vtb + t + krow * 8);

        f32x16 sc = zero16();
        sc = __builtin_amdgcn_mfma_f32_32x32x16_bf16(khc, qfl, sc, 0, 0, 0);
        sc = __builtin_amdgcn_mfma_f32_32x32x16_bf16(klc, qfh, sc, 0, 0, 0);
        sc = __builtin_amdgcn_mfma_f32_32x32x16_bf16(khc, qfh, sc, 0, 0, 0);
        bool tail = (t + 32 > L);                    // wave-uniform

        // tile max per query (pads excluded — K pads are poison/NaN)
        float tmax = -3.0e38f;
        if (!tail) {
#pragma unroll
            for (int r = 0; r < 16; r++) tmax = fmaxf(tmax, sc[r]);
        } else {
#pragma unroll
            for (int r = 0; r < 16; r++) {
                int key = t + (r & 3) + 8 * (r >> 2) + 4 * kg;
                if (key < L) tmax = fmaxf(tmax, sc[r]);
            }
        }
        tmax = fmaxf(tmax, __shfl_xor(tmax, 32, 64));    // per-query (m)

        if (__any(tmax > m_run + 8.0f)) {                // defer-8 trigger
            float mnew = fmaxf(m_run, tmax);
            float s = __builtin_amdgcn_exp2f(m_run - mnew);
            if (kg == 0) scl[m] = s;                     // QK-layout -> LDS
            m_run = mnew;
            f32x4 s0 = *(const f32x4*)(scl + krow * 4);       // PV-layout read
            f32x4 s1 = *(const f32x4*)(scl + krow * 4 + 16);
#pragma unroll
            for (int j = 0; j < 4; j++) {
                o0[j] *= s0[j]; l0[j] *= s0[j];
                o1[j] *= s1[j]; l1[j] *= s1[j];
            }
        }

#pragma unroll
        for (int rg = 0; rg < 4; rg++) {
            float e0 = __builtin_amdgcn_exp2f(sc[rg * 4 + 0] - m_run);
            float e1 = __builtin_amdgcn_exp2f(sc[rg * 4 + 1] - m_run);
            float e2 = __builtin_amdgcn_exp2f(sc[rg * 4 + 2] - m_run);
            float e3 = __builtin_amdgcn_exp2f(sc[rg * 4 + 3] - m_run);
            if (tail) {                              // zero pad-key weights
                int kb = t + rg * 8 + kg * 4;
                e0 = (kb + 0 < L) ? e0 : 0.f;
                e1 = (kb + 1 < L) ? e1 : 0.f;
                e2 = (kb + 2 < L) ? e2 : 0.f;
                e3 = (kb + 3 < L) ? e3 : 0.f;
            }
            u32x2 pk;
            pk[0] = __builtin_amdgcn_perm(__builtin_bit_cast(u32, e1),
                                          __builtin_bit_cast(u32, e0), 0x07060302u);
            pk[1] = __builtin_amdgcn_perm(__builtin_bit_cast(u32, e3),
                                          __builtin_bit_cast(u32, e2), 0x07060302u);
            *(u32x2*)(pwb + ((rg ^ msw) * 8)) = pk;   // keys rg*8+4kg..+3, query m
        }
        bf16x8 p0 = *(const bf16x8*)pr0;
        bf16x8 p1 = *(const bf16x8*)pr1;
        o0 = __builtin_amdgcn_mfma_f32_16x16x32_bf16(p0, vf, o0, 0, 0, 0);
        o1 = __builtin_amdgcn_mfma_f32_16x16x32_bf16(p1, vf, o1, 0, 0, 0);
        l0 = __builtin_amdgcn_mfma_f32_16x16x32_bf16(p0, ones, l0, 0, 0, 0);
        l1 = __builtin_amdgcn_mfma_f32_16x16x32_bf16(p1, ones, l1, 0, 0, 0);
        khc = khn; klc = kln;
    }

    // ---- epilogue: normalize in-wave, write AO slice to swizzled LDS tile ----
    int slot0 = (h == 0) ? 0 : h + 1;
#pragma unroll
    for (int j = 0; j < 4; j++) {
        int row0 = krow * 4 + j;
        u16 v0 = f2b_rne(o0[j] * __builtin_amdgcn_rcpf(l0[j]));
        u16 v1 = f2b_rne(o1[j] * __builtin_amdgcn_rcpf(l1[j]));
        int col = slot0 * 16 + q16;
        st_ao(aob, row0,      col, v0);
        st_ao(aob, row0 + 16, col, v1);
        if (h == 1) {                         // buggy-concat duplicate slot
            st_ao(aob, row0,      16 + q16, v0);
            st_ao(aob, row0 + 16, 16 + q16, v1);
        }
    }

    __syncthreads();                          // AO tile complete
    if (threadIdx.x >= 256) return;           // waves 4-6 done

    // ---- fin (waves 0-3): out[qs..qs+31][0..127] = AO @ lw^T + lb ----
    int ct2 = threadIdx.x >> 6;
    int c = ct2 * 32 + m;
    int r0 = b * 2048 + qs;
    f32x16 acc = zero16();
#pragma unroll 4
    for (int kk = 0; kk < 128; kk += 16) {
        int col0 = kk + kg * 8;
        int blk = (col0 >> 3) ^ (m & 15);
        bf16x8 af = *(const bf16x8*)(aob + m * 128 + blk * 8);
        const float* wp2 = lw + (size_t)c * 128 + col0;
        f32x4 w0 = *(const f32x4*)wp2;
        f32x4 w1 = *(const f32x4*)(wp2 + 4);
        BF8 bfr;
#pragma unroll
        for (int j = 0; j < 4; j++) {
            bfr.s[j]     = f2b_rne(w0[j]);
            bfr.s[4 + j] = f2b_rne(w1[j]);
        }
        acc = __builtin_amdgcn_mfma_f32_32x32x16_bf16(af, bfr.v, acc, 0, 0, 0);
    }
    float bias = lb[c];
#pragma unroll
    for (int r = 0; r < 16; r++) {
        int row = (r & 3) + 8 * (r >> 2) + 4 * kg;
        out[(size_t)(r0 + row) * 128 + c] = acc[r] + bias;
    }
}

// ---------------------------------------------------------------------------
extern "C" void kernel_launch(void* const* d_in, const int* in_sizes, int n_in,
                              void* d_out, int out_size, void* d_ws, size_t ws_size,
                              hipStream_t stream)
{
    const float* x    = (const float*)d_in[0];
    const int*   mask = (const int*)d_in[1];
    const float* wq   = (const float*)d_in[2];
    const float* wk   = (const float*)d_in[3];
    const float* wv   = (const float*)d_in[4];
    const float* lw   = (const float*)d_in[5];
    const float* lb   = (const float*)d_in[6];
    float* out = (float*)d_out;

    char* ws = (char*)d_ws;
    u16* Qph = (u16*)(ws + 0 * 2097152);
    u16* Qpl = (u16*)(ws + 1 * 2097152);
    u16* Kph = (u16*)(ws + 2 * 2097152);
    u16* Kpl = (u16*)(ws + 3 * 2097152);
    u16* VT  = (u16*)(ws + 4 * 2097152);
    int* Larr = (int*)(ws + 5 * 2097152);            // 4 int

    proj_kernel<<<dim3(256, 3), 256, 0, stream>>>(x, wq, wk, wv, mask, Larr,
                                                  Qph, Qpl, Kph, Kpl, VT);
    attn_kernel<<<256, 448, 0, stream>>>(Qph, Qpl, Kph, Kpl, VT, Larr,
                                         lw, lb, out);
}